// Round 1
// 1125.693 us; speedup vs baseline: 1.1092x; 1.1092x over previous
//
#include <hip/hip_runtime.h>

typedef __attribute__((ext_vector_type(8))) short short8;
typedef __attribute__((ext_vector_type(4))) float f32x4;
typedef __attribute__((ext_vector_type(4))) unsigned short us4;
typedef unsigned short u16;

__device__ __forceinline__ u16 f2bf(float f) {
    unsigned u = __builtin_bit_cast(unsigned, f);
    return (u16)((u + 0x7fffu + ((u >> 16) & 1u)) >> 16);
}
__device__ __forceinline__ float bf2f(u16 h) {
    unsigned u = ((unsigned)h) << 16;
    return __builtin_bit_cast(float, u);
}
__device__ __forceinline__ void async16(const void* g, void* l) {
    __builtin_amdgcn_global_load_lds((const __attribute__((address_space(1))) unsigned int*)g,
                                     (__attribute__((address_space(3))) unsigned int*)l,
                                     16, 0, 0);
}

// ---------------- elementwise fp32 -> bf16 conversion ----------------
__global__ __launch_bounds__(256) void cvt_k(const float* __restrict__ in, u16* __restrict__ out) {
    int i = (blockIdx.x * 256 + threadIdx.x) * 4;
    f32x4 v = *(const f32x4*)(in + i);
    us4 o;
    o[0] = f2bf(v[0]); o[1] = f2bf(v[1]); o[2] = f2bf(v[2]); o[3] = f2bf(v[3]);
    *(us4*)(out + i) = o;
}

// ---------------- rmsnorm (keeps source bug: MULTIPLY by sqrt(var+eps)) ----------------
__global__ __launch_bounds__(256) void rmsnorm_k(const float* __restrict__ X, const float* __restrict__ g,
                                                 u16* __restrict__ O) {
    const int row = blockIdx.x, tid = threadIdx.x;
    const float* xr = X + (long)row * 2048 + tid * 8;
    f32x4 v0 = *(const f32x4*)xr;
    f32x4 v1 = *(const f32x4*)(xr + 4);
    float ss = v0[0]*v0[0] + v0[1]*v0[1] + v0[2]*v0[2] + v0[3]*v0[3]
             + v1[0]*v1[0] + v1[1]*v1[1] + v1[2]*v1[2] + v1[3]*v1[3];
#pragma unroll
    for (int m = 1; m < 64; m <<= 1) ss += __shfl_xor(ss, m, 64);
    __shared__ float wsum[4];
    if ((tid & 63) == 0) wsum[tid >> 6] = ss;
    __syncthreads();
    float tot = wsum[0] + wsum[1] + wsum[2] + wsum[3];
    const float sc = sqrtf(tot * (1.0f / 2048.0f) + 1e-6f);
    const float* gr = g + tid * 8;
    f32x4 g0 = *(const f32x4*)gr, g1 = *(const f32x4*)(gr + 4);
    us4 o0, o1;
    o0[0] = f2bf(v0[0] * sc * g0[0]); o0[1] = f2bf(v0[1] * sc * g0[1]);
    o0[2] = f2bf(v0[2] * sc * g0[2]); o0[3] = f2bf(v0[3] * sc * g0[3]);
    o1[0] = f2bf(v1[0] * sc * g1[0]); o1[1] = f2bf(v1[1] * sc * g1[1]);
    o1[2] = f2bf(v1[2] * sc * g1[2]); o1[3] = f2bf(v1[3] * sc * g1[3]);
    u16* op = O + (long)row * 2048 + tid * 8;
    *(us4*)op = o0;
    *(us4*)(op + 4) = o1;
}

// ---------------- 8-phase 256xBN GEMM: C = A * W^T (bf16 in, fp32 acc) ----------------
// m201 template: BM=256, BK=64 (2 k-half slots of 32), 512 thr = 8 waves, double-buffered
// LDS (2 K-tiles), 8 phases per 2 K-tiles, counted vmcnt (6 / 4), raw s_barrier, setprio,
// 16B-chunk XOR swizzle c^=(row>>1)&3 (pre-swizzled global source, linear gload_lds dest).
// Slot read windows: A.k0:{p1,p2} A.k1:{p3,p4} B.k0:{p1} B.k1:{p3} (buf0; +4 for buf1).
// Stage schedule (iter i = tiles 2i,2i+1): p1:A1k1(t+1) p2:B0k0(t+2) p3:A0k0(t+2)
// p4:B0k1(t+2)+vmcnt p5:A0k1(t+2) p6:B1k0(t+3) p7:A1k0... p8:B1k1(t+3)+vmcnt.
// Each stage is issued after the 2nd barrier of its slot's last reading phase (safe), and
// each slot is FIFO-drained by the phase-4/8 vmcnt before its first reading phase.
enum { M_QKV = 0, M_VT = 1, M_H1 = 2, M_RELU = 3, M_MUL = 4, M_ADD = 5 };

template <int MODE, int BN>
__global__ __launch_bounds__(512, 2) void gemm8p(const u16* __restrict__ A, const u16* __restrict__ W,
                                                 const float* __restrict__ bias, const float* resid,
                                                 const u16* aux, void* out,
                                                 int N, int K, float scale) {
    constexpr int MF = BN / 32;      // m-frags per wave (8 or 4)
    constexpr int HF = MF / 2;       // m-frags per phase
    constexpr int NF = 4;            // n-frags per wave
    constexpr int BSLOT = BN * 32;   // u16 elems per B k-half slot
    __shared__ alignas(16) u16 As[2][2][8192];
    __shared__ alignas(16) u16 Bs[2][2][BSLOT];

    const int tid = threadIdx.x, wv = tid >> 6, lane = tid & 63;
    const int q4 = lane >> 4, lr = lane & 15;
    const int wm = (BN == 256) ? (wv >> 2) * 128 : (wv >> 1) * 64;
    const int wn = (BN == 256) ? (wv & 3) * 64 : (wv & 1) * 64;

    // bijective XCD-chunked workgroup swizzle (m204)
    const int ntn = N / BN;
    int wg = blockIdx.x;
    {
        const int nwg = gridDim.x, q = nwg >> 3, r = nwg & 7, x = wg & 7, l = wg >> 3;
        wg = (x < r ? x * (q + 1) : r * (q + 1) + (x - r) * q) + l;
    }
    const long m0 = (long)(wg / ntn) * 256;
    const int n0 = (wg % ntn) * BN;

    // swizzled LDS fragment-read offsets (elems): row*32 + (q4 ^ ((row>>1)&3))*8
    const int cswz = (q4 ^ ((lr >> 1) & 3)) * 8;
    const int a_rd = (wm + lr) * 32 + cswz;
    const int b_rd = (wn + lr) * 32 + cswz;

    // staging: linear LDS dest (wave base + lane*16B), pre-swizzled global source
    const int srow = tid >> 2;                          // row within 128-row round
    const int slc = ((tid & 3) ^ ((srow >> 1) & 3)) * 8; // logical chunk elem offset
    const u16* gA0 = A + (m0 + srow) * (long)K + slc;
    const u16* gA1 = gA0 + 128 * (long)K;
    const u16* gB0 = W + ((long)n0 + srow) * K + slc;
    const u16* gB1 = (BN == 256) ? gB0 + 128 * (long)K : gB0;

    f32x4 acc[MF][NF] = {};
    short8 bfr[NF];

#define STAGEA(BUF, KS, KOFF) do {                       \
        u16* d_ = &As[BUF][KS][wv * 512];                \
        async16(gA0 + (KOFF), d_);                       \
        async16(gA1 + (KOFF), d_ + 4096); } while (0)
#define STAGEB(BUF, KS, KOFF) do {                       \
        u16* d_ = &Bs[BUF][KS][wv * 512];                \
        async16(gB0 + (KOFF), d_);                       \
        if (BN == 256) async16(gB1 + (KOFF), d_ + 4096); } while (0)
#define VMW_N do { if (BN == 256) asm volatile("s_waitcnt vmcnt(6)" ::: "memory"); \
                   else           asm volatile("s_waitcnt vmcnt(4)" ::: "memory"); } while (0)
#define VMW_0 asm volatile("s_waitcnt vmcnt(0)" ::: "memory")
#define PHASE(BUF, KS, FSEL, STAGE_, VMW_) do {                                              \
        short8 afr_[HF];                                                                     \
        _Pragma("unroll") for (int m_ = 0; m_ < HF; m_++)                                    \
            afr_[m_] = *(const short8*)(&As[BUF][KS][a_rd + ((FSEL) * HF + m_) * 512]);      \
        if ((FSEL) == 0) {                                                                   \
            _Pragma("unroll") for (int n_ = 0; n_ < NF; n_++)                                \
                bfr[n_] = *(const short8*)(&Bs[BUF][KS][b_rd + n_ * 512]);                   \
        }                                                                                    \
        STAGE_;                                                                              \
        __builtin_amdgcn_s_barrier();                                                        \
        asm volatile("s_waitcnt lgkmcnt(0)");                                                \
        __builtin_amdgcn_s_setprio(1);                                                       \
        _Pragma("unroll") for (int m_ = 0; m_ < HF; m_++)                                    \
            _Pragma("unroll") for (int n_ = 0; n_ < NF; n_++)                                \
                acc[(FSEL) * HF + m_][n_] = __builtin_amdgcn_mfma_f32_16x16x32_bf16(         \
                    afr_[m_], bfr[n_], acc[(FSEL) * HF + m_][n_], 0, 0, 0);                  \
        __builtin_amdgcn_s_setprio(0);                                                       \
        VMW_;                                                                                \
        __builtin_amdgcn_sched_barrier(0);                                                   \
        __builtin_amdgcn_s_barrier();                                                        \
    } while (0)

    // prologue: tile0 (all 4 slots) + tile1 (B.k0, A.k0, B.k1); A.k1(t1) staged at p1.
    STAGEB(0, 0, 0);  STAGEA(0, 0, 0);  STAGEB(0, 1, 32); STAGEA(0, 1, 32);
    STAGEB(1, 0, 64); STAGEA(1, 0, 64); STAGEB(1, 1, 96);
    VMW_N;  // tile0 fully landed; tile1's 3 staged slots remain in flight
    __builtin_amdgcn_s_barrier();

    const int NI = K >> 7;  // K-tile pairs
    int k0 = 0;             // elem offset of tile 2i
    for (int i = 0; i < NI - 1; ++i, k0 += 128) {
        PHASE(0, 0, 0, STAGEA(1, 1, k0 + 96),  );
        PHASE(0, 0, 1, STAGEB(0, 0, k0 + 128), );
        PHASE(0, 1, 0, STAGEA(0, 0, k0 + 128), );
        PHASE(0, 1, 1, STAGEB(0, 1, k0 + 160), VMW_N);
        PHASE(1, 0, 0, STAGEA(0, 1, k0 + 160), );
        PHASE(1, 0, 1, STAGEB(1, 0, k0 + 192), );
        PHASE(1, 1, 0, STAGEA(1, 0, k0 + 192), );
        PHASE(1, 1, 1, STAGEB(1, 1, k0 + 224), VMW_N);
    }
    // epilogue iteration: last 2 tiles; p1 completes tile NT-1's staging, then drain.
    PHASE(0, 0, 0, STAGEA(1, 1, k0 + 96), );
    PHASE(0, 0, 1, , );
    PHASE(0, 1, 0, , );
    PHASE(0, 1, 1, , VMW_0);
    PHASE(1, 0, 0, , );
    PHASE(1, 0, 1, , );
    PHASE(1, 1, 0, , );
    PHASE(1, 1, 1, , );

#undef PHASE
#undef VMW_0
#undef VMW_N
#undef STAGEB
#undef STAGEA

    // epilogue: C row = q4*4+r, col = lr within each 16x16 fragment
#pragma unroll
    for (int m = 0; m < MF; m++) {
#pragma unroll
        for (int n = 0; n < NF; n++) {
            const int gn = n0 + wn + n * 16 + lr;
#pragma unroll
            for (int r = 0; r < 4; r++) {
                const long gm = m0 + wm + m * 16 + q4 * 4 + r;
                float v = acc[m][n][r];
                if constexpr (MODE == M_QKV) {
                    v = (v + bias[gn]) * scale;
                    ((u16*)out)[gm * N + gn] = f2bf(v);
                } else if constexpr (MODE == M_VT) {
                    v = v + bias[gm];
                    const long b = gn >> 11, s = gn & 2047;
                    ((u16*)out)[(b << 22) + gm * 2048 + s] = f2bf(v);
                } else if constexpr (MODE == M_H1) {
                    ((float*)out)[gm * N + gn] = v + bias[gn] + resid[gm * N + gn];
                } else if constexpr (MODE == M_RELU) {
                    ((u16*)out)[gm * N + gn] = f2bf(fmaxf(v, 0.0f));
                } else if constexpr (MODE == M_MUL) {
                    ((u16*)out)[gm * N + gn] = f2bf(v * bf2f(aux[gm * N + gn]));
                } else {  // M_ADD
                    ((float*)out)[gm * N + gn] = v + resid[gm * N + gn];
                }
            }
        }
    }
}

// ---------------- flash attention, computes O^T directly into the scrambled layout ----------------
__global__ __launch_bounds__(512) void attn_kernel(const u16* __restrict__ Q, const u16* __restrict__ Km,
                                                   const u16* __restrict__ Vt, u16* __restrict__ Oscr) {
    __shared__ u16 Ks[128 * 128];
    __shared__ u16 Vs[128 * 128];
    __shared__ u16 Ps[8][16 * 136];  // per-wave P strip, pitch 136 (8/bank on b128 reads)
    __shared__ float abuf[8][16];
    __shared__ float lbuf[8][16];
    const int tid = threadIdx.x, w = tid >> 6, lane = tid & 63;
    const int q4 = lane >> 4, lr = lane & 15;
    const int bh = blockIdx.y, b = bh >> 4, h = bh & 15;
    const int sw = blockIdx.x * 128 + w * 16;  // this wave's 16 query rows
    const long qkbase = ((long)b * 2048) * 2048 + h * 128;
    const long vtbase = ((long)b * 2048 + h * 128) * 2048;

    short8 qf[4];
    {
        const u16* qr = Q + qkbase + (long)(sw + lr) * 2048 + q4 * 8;
#pragma unroll
        for (int kk = 0; kk < 4; kk++) qf[kk] = *(const short8*)(qr + kk * 32);
    }
    float m_i[4], l_i[4];
#pragma unroll
    for (int r = 0; r < 4; r++) { m_i[r] = -1e30f; l_i[r] = 0.0f; }
    f32x4 oacc[8] = {};

    for (int t0 = 0; t0 < 2048; t0 += 128) {
        __syncthreads();
#pragma unroll
        for (int i = 0; i < 4; i++) {
            const int c = i * 512 + tid;           // linear 16B chunk 0..2047
            const int row = c >> 4;                // tile row 0..127
            const int lc = (c & 15) ^ (row & 15);  // logical chunk fetched into physical slot
            async16(Km + qkbase + (long)(t0 + row) * 2048 + lc * 8, (u16*)Ks + (i * 512 + w * 64) * 8);
            async16(Vt + vtbase + (long)row * 2048 + t0 + lc * 8, (u16*)Vs + (i * 512 + w * 64) * 8);
        }
        __syncthreads();
        // S strip [16 s][128 t] = q * K^T (scale pre-folded into q)
        f32x4 sacc[8] = {};
#pragma unroll
        for (int kk = 0; kk < 4; kk++) {
#pragma unroll
            for (int n = 0; n < 8; n++) {
                const int pc = (kk * 4 + q4) ^ lr;  // swizzled chunk
                short8 kf = *(const short8*)(Ks + ((n * 16 + lr) * 16 + pc) * 8);
                sacc[n] = __builtin_amdgcn_mfma_f32_16x16x32_bf16(qf[kk], kf, sacc[n], 0, 0, 0);
            }
        }
        // online softmax per s-row (row = q4*4+r, replicated across the 16 lanes of the quad)
        float al[4];
#pragma unroll
        for (int r = 0; r < 4; r++) {
            float mx = sacc[0][r];
#pragma unroll
            for (int n = 1; n < 8; n++) mx = fmaxf(mx, sacc[n][r]);
#pragma unroll
            for (int msk = 1; msk < 16; msk <<= 1) mx = fmaxf(mx, __shfl_xor(mx, msk, 64));
            const float mn = fmaxf(m_i[r], mx);
            al[r] = __expf(m_i[r] - mn);
            float rs = 0.0f;
#pragma unroll
            for (int n = 0; n < 8; n++) {
                float p = __expf(sacc[n][r] - mn);
                sacc[n][r] = p;
                rs += p;
            }
#pragma unroll
            for (int msk = 1; msk < 16; msk <<= 1) rs += __shfl_xor(rs, msk, 64);
            l_i[r] = l_i[r] * al[r] + rs;
            m_i[r] = mn;
        }
        // P -> LDS (bf16), alpha broadcast
#pragma unroll
        for (int n = 0; n < 8; n++)
#pragma unroll
            for (int r = 0; r < 4; r++)
                Ps[w][(q4 * 4 + r) * 136 + n * 16 + lr] = f2bf(sacc[n][r]);
        if (lr == 0) {
#pragma unroll
            for (int r = 0; r < 4; r++) abuf[w][q4 * 4 + r] = al[r];
        }
        __syncthreads();
        const float a_s = abuf[w][lr];
#pragma unroll
        for (int mm = 0; mm < 8; mm++) oacc[mm] *= a_s;
        // O^T[d][s] += Vt_tile(rows d) * P^T : A-frag from Vs rows, B-frag from Ps rows
#pragma unroll
        for (int kk = 0; kk < 4; kk++) {
            short8 pf = *(const short8*)(&Ps[w][lr * 136 + kk * 32 + q4 * 8]);
            const int pc = (kk * 4 + q4) ^ lr;
#pragma unroll
            for (int mm = 0; mm < 8; mm++) {
                short8 vf = *(const short8*)(Vs + ((mm * 16 + lr) * 16 + pc) * 8);
                oacc[mm] = __builtin_amdgcn_mfma_f32_16x16x32_bf16(vf, pf, oacc[mm], 0, 0, 0);
            }
        }
    }
    if (lr == 0) {
#pragma unroll
        for (int r = 0; r < 4; r++) lbuf[w][q4 * 4 + r] = l_i[r];
    }
    __syncthreads();
    const float linv = 1.0f / lbuf[w][lr];
    // write O^T: row d = mm*16+q4*4+r, col s = sw+lr (16-lane contiguous bf16 stores)
#pragma unroll
    for (int mm = 0; mm < 8; mm++) {
#pragma unroll
        for (int r = 0; r < 4; r++) {
            const int d = mm * 16 + q4 * 4 + r;
            Oscr[vtbase + (long)d * 2048 + sw + lr] = f2bf(oacc[mm][r] * linv);
        }
    }
}

// ---------------- launch ----------------
// Workspace budget (112 MB total), lifetime-aliased:
//   [0,16)MB   : xn  -> scr -> hn      (sequential lives)
//   [16,80)MB  : qb|kb|vt (16 each) -> grelu (64) -> inter (in-place)
//   [80,112)MB : JIT bf16 weight region: {wq,wk,wv,wo} -> wg -> wu -> wd
//   h1 lives in d_out (fp32, fully overwritten before first read).
extern "C" void kernel_launch(void* const* d_in, const int* in_sizes, int n_in,
                              void* d_out, int out_size, void* d_ws, size_t ws_size,
                              hipStream_t stream) {
    const float* x  = (const float*)d_in[0];
    const float* wq = (const float*)d_in[1];
    const float* bq = (const float*)d_in[2];
    const float* wk = (const float*)d_in[3];
    const float* bk = (const float*)d_in[4];
    const float* wv = (const float*)d_in[5];
    const float* bv = (const float*)d_in[6];
    const float* wo = (const float*)d_in[7];
    const float* bo = (const float*)d_in[8];
    const float* wg = (const float*)d_in[9];
    const float* wu = (const float*)d_in[10];
    const float* wd = (const float*)d_in[11];
    const float* ga = (const float*)d_in[12];
    const float* gf = (const float*)d_in[13];

    char* ws = (char*)d_ws;
    const size_t MB = (size_t)1 << 20;
    u16*  xn    = (u16*)(ws + 0);
    u16*  scr   = (u16*)(ws + 0);            // alias: xn dead after projections
    u16*  hn    = (u16*)(ws + 0);            // alias: scr dead after o-proj
    u16*  qb    = (u16*)(ws + 16 * MB);
    u16*  kb    = (u16*)(ws + 32 * MB);
    u16*  vt    = (u16*)(ws + 48 * MB);
    u16*  grelu = (u16*)(ws + 16 * MB);      // 64 MB, alias over qb/kb/vt/pad
    u16*  inter = grelu;                     // in-place relu(g)*u
    u16*  wreg  = (u16*)(ws + 80 * MB);      // 32 MB JIT weight region
    u16*  wq_b  = wreg;
    u16*  wk_b  = wreg + 4 * MB;             // u16 elements: 8MB bytes each
    u16*  wv_b  = wreg + 8 * MB;
    u16*  wo_b  = wreg + 12 * MB;
    u16*  wbig  = wreg;                      // wg -> wu -> wd reuse
    float* h1   = (float*)d_out;

    // phase-A weights fp32 -> bf16
    cvt_k<<<4096, 256, 0, stream>>>(wq, wq_b);
    cvt_k<<<4096, 256, 0, stream>>>(wk, wk_b);
    cvt_k<<<4096, 256, 0, stream>>>(wv, wv_b);
    cvt_k<<<4096, 256, 0, stream>>>(wo, wo_b);

    rmsnorm_k<<<4096, 256, 0, stream>>>(x, ga, xn);

    const float qscale = 0.08838834764831843f;  // 1/sqrt(128)
    // Q: M=4096,N=2048 -> (4096/256)*(2048/128) = 256 wgs
    gemm8p<M_QKV, 128><<<256, 512, 0, stream>>>(xn, wq_b, bq, nullptr, nullptr, qb, 2048, 2048, qscale);
    gemm8p<M_QKV, 128><<<256, 512, 0, stream>>>(xn, wk_b, bk, nullptr, nullptr, kb, 2048, 2048, 1.0f);
    // V^T: roles swapped -> C[nv][(b,s)] = wv . xn^T, stored [b][nv][s]; M=2048,N=4096 -> 8*32=256 wgs
    gemm8p<M_VT, 128><<<256, 512, 0, stream>>>(wv_b, xn, bv, nullptr, nullptr, vt, 4096, 2048, 1.0f);

    attn_kernel<<<dim3(16, 32), 512, 0, stream>>>(qb, kb, vt, scr);

    // out-proj + residual: h1 = x + scr @ wo^T + bo   (h1 lives in d_out); 16*16=256 wgs
    gemm8p<M_H1, 128><<<256, 512, 0, stream>>>(scr, wo_b, bo, x, nullptr, h1, 2048, 2048, 1.0f);

    cvt_k<<<16384, 256, 0, stream>>>(wg, wbig);          // wq..wo dead now
    rmsnorm_k<<<4096, 256, 0, stream>>>(h1, gf, hn);

    // M=4096,N=8192 -> (4096/256)*(8192/256) = 512 wgs
    gemm8p<M_RELU, 256><<<512, 512, 0, stream>>>(hn, wbig, nullptr, nullptr, nullptr, grelu, 8192, 2048, 1.0f);

    cvt_k<<<16384, 256, 0, stream>>>(wu, wbig);          // wg dead
    gemm8p<M_MUL, 256><<<512, 512, 0, stream>>>(hn, wbig, nullptr, nullptr, grelu, inter, 8192, 2048, 1.0f);

    cvt_k<<<16384, 256, 0, stream>>>(wd, wbig);          // wu dead
    // down-proj: M=4096,N=2048,K=8192 -> 256 wgs
    gemm8p<M_ADD, 128><<<256, 512, 0, stream>>>(inter, wbig, nullptr, h1, nullptr, d_out, 2048, 8192, 1.0f);
}

// Round 3
// 1099.616 us; speedup vs baseline: 1.1355x; 1.0237x over previous
//
#include <hip/hip_runtime.h>

typedef __attribute__((ext_vector_type(8))) short short8;
typedef __attribute__((ext_vector_type(4))) float f32x4;
typedef __attribute__((ext_vector_type(4))) unsigned short us4;
typedef unsigned short u16;

__device__ __forceinline__ u16 f2bf(float f) {
    unsigned u = __builtin_bit_cast(unsigned, f);
    return (u16)((u + 0x7fffu + ((u >> 16) & 1u)) >> 16);
}
__device__ __forceinline__ float bf2f(u16 h) {
    unsigned u = ((unsigned)h) << 16;
    return __builtin_bit_cast(float, u);
}
__device__ __forceinline__ void async16(const void* g, void* l) {
    __builtin_amdgcn_global_load_lds((const __attribute__((address_space(1))) unsigned int*)g,
                                     (__attribute__((address_space(3))) unsigned int*)l,
                                     16, 0, 0);
}

// ---------------- elementwise fp32 -> bf16 conversion ----------------
__global__ __launch_bounds__(256) void cvt_k(const float* __restrict__ in, u16* __restrict__ out) {
    int i = (blockIdx.x * 256 + threadIdx.x) * 4;
    f32x4 v = *(const f32x4*)(in + i);
    us4 o;
    o[0] = f2bf(v[0]); o[1] = f2bf(v[1]); o[2] = f2bf(v[2]); o[3] = f2bf(v[3]);
    *(us4*)(out + i) = o;
}

// ---------------- rmsnorm (keeps source bug: MULTIPLY by sqrt(var+eps)) ----------------
__global__ __launch_bounds__(256) void rmsnorm_k(const float* __restrict__ X, const float* __restrict__ g,
                                                 u16* __restrict__ O) {
    const int row = blockIdx.x, tid = threadIdx.x;
    const float* xr = X + (long)row * 2048 + tid * 8;
    f32x4 v0 = *(const f32x4*)xr;
    f32x4 v1 = *(const f32x4*)(xr + 4);
    float ss = v0[0]*v0[0] + v0[1]*v0[1] + v0[2]*v0[2] + v0[3]*v0[3]
             + v1[0]*v1[0] + v1[1]*v1[1] + v1[2]*v1[2] + v1[3]*v1[3];
#pragma unroll
    for (int m = 1; m < 64; m <<= 1) ss += __shfl_xor(ss, m, 64);
    __shared__ float wsum[4];
    if ((tid & 63) == 0) wsum[tid >> 6] = ss;
    __syncthreads();
    float tot = wsum[0] + wsum[1] + wsum[2] + wsum[3];
    const float sc = sqrtf(tot * (1.0f / 2048.0f) + 1e-6f);
    const float* gr = g + tid * 8;
    f32x4 g0 = *(const f32x4*)gr, g1 = *(const f32x4*)(gr + 4);
    us4 o0, o1;
    o0[0] = f2bf(v0[0] * sc * g0[0]); o0[1] = f2bf(v0[1] * sc * g0[1]);
    o0[2] = f2bf(v0[2] * sc * g0[2]); o0[3] = f2bf(v0[3] * sc * g0[3]);
    o1[0] = f2bf(v1[0] * sc * g1[0]); o1[1] = f2bf(v1[1] * sc * g1[1]);
    o1[2] = f2bf(v1[2] * sc * g1[2]); o1[3] = f2bf(v1[3] * sc * g1[3]);
    u16* op = O + (long)row * 2048 + tid * 8;
    *(us4*)op = o0;
    *(us4*)(op + 4) = o1;
}

// ---------------- 8/4-phase 256xBN GEMM: C = A * W^T (bf16 in, fp32 acc) ----------------
// m201 template: BM=256, BK=64 (2 k-half slots of 32), 512 thr = 8 waves, double-buffered
// LDS (2 K-tiles), counted vmcnt, raw s_barrier, setprio, 16B-chunk XOR swizzle
// c^=(row>>1)&3 (pre-swizzled global source, linear gload_lds dest).
// BN=256: 8 phases / 2 K-tiles, per phase 16 MFMA (HF=4 of MF=8 m-frags), vmcnt(6) at P4/P8.
// BN=128: merged 4 phases / 2 K-tiles, each phase = one full k-half slot, 16 MFMA.
//   HAZARD RULE (round-2 failure): a slot must NEVER be staged in the phase that reads it —
//   the gload_lds write-back (L2 ~200-300cy) can land before a deep-queued ds_read samples
//   the slot. Every stage here issues exactly ONE phase after its slot's read:
//     P1 rd{A00,B00} st{A11,B11}@+96 | P2 rd{A01,B01} st{A00,B00}@+128
//     P3 rd{A10,B10} st{A01,B01}@+160 | P4 rd{A11,B11} st{A10,B10}@+192
//   3 loads/phase (2A+1B); every phase ends vmcnt(6) = completes exactly the triple the
//   next phase reads (staged data lands 3 phases after issue). Epilogue drains 6/3/0.
enum { M_QKV = 0, M_VT = 1, M_H1 = 2, M_RELU = 3, M_MUL = 4, M_ADD = 5 };

template <int MODE, int BN>
__global__ __launch_bounds__(512, 2) void gemm8p(const u16* __restrict__ A, const u16* __restrict__ W,
                                                 const float* __restrict__ bias, const float* resid,
                                                 const u16* aux, void* out,
                                                 int N, int K, float scale) {
    constexpr int MF = BN / 32;      // m-frags per wave (8 or 4)
    constexpr int HF = 4;            // m-frags per phase (both variants)
    constexpr int NF = 4;            // n-frags per wave
    constexpr int BSLOT = BN * 32;   // u16 elems per B k-half slot
    __shared__ alignas(16) u16 As[2][2][8192];
    __shared__ alignas(16) u16 Bs[2][2][BSLOT];

    const int tid = threadIdx.x, wv = tid >> 6, lane = tid & 63;
    const int q4 = lane >> 4, lr = lane & 15;
    const int wm = (BN == 256) ? (wv >> 2) * 128 : (wv >> 1) * 64;
    const int wn = (BN == 256) ? (wv & 3) * 64 : (wv & 1) * 64;

    // bijective XCD-chunked workgroup swizzle (m204)
    const int ntn = N / BN;
    int wg = blockIdx.x;
    {
        const int nwg = gridDim.x, q = nwg >> 3, r = nwg & 7, x = wg & 7, l = wg >> 3;
        wg = (x < r ? x * (q + 1) : r * (q + 1) + (x - r) * q) + l;
    }
    const long m0 = (long)(wg / ntn) * 256;
    const int n0 = (wg % ntn) * BN;

    // swizzled LDS fragment-read offsets (elems): row*32 + (q4 ^ ((row>>1)&3))*8
    const int cswz = (q4 ^ ((lr >> 1) & 3)) * 8;
    const int a_rd = (wm + lr) * 32 + cswz;
    const int b_rd = (wn + lr) * 32 + cswz;

    // staging: linear LDS dest (wave base + lane*16B), pre-swizzled global source
    const int srow = tid >> 2;                          // row within 128-row round
    const int slc = ((tid & 3) ^ ((srow >> 1) & 3)) * 8; // logical chunk elem offset
    const u16* gA0 = A + (m0 + srow) * (long)K + slc;
    const u16* gA1 = gA0 + 128 * (long)K;
    const u16* gB0 = W + ((long)n0 + srow) * K + slc;
    const u16* gB1 = (BN == 256) ? gB0 + 128 * (long)K : gB0;

    f32x4 acc[MF][NF] = {};
    short8 bfr[NF];

#define STAGEA(BUF, KS, KOFF) do {                       \
        u16* d_ = &As[BUF][KS][wv * 512];                \
        async16(gA0 + (KOFF), d_);                       \
        async16(gA1 + (KOFF), d_ + 4096); } while (0)
#define STAGEB(BUF, KS, KOFF) do {                       \
        u16* d_ = &Bs[BUF][KS][wv * 512];                \
        async16(gB0 + (KOFF), d_);                       \
        if (BN == 256) async16(gB1 + (KOFF), d_ + 4096); } while (0)
#define VM(N) asm volatile("s_waitcnt vmcnt(" #N ")" ::: "memory")
#define PHASE(BUF, KS, FSEL, RDB, STAGE_, VMW_) do {                                         \
        short8 afr_[HF];                                                                     \
        _Pragma("unroll") for (int m_ = 0; m_ < HF; m_++)                                    \
            afr_[m_] = *(const short8*)(&As[BUF][KS][a_rd + ((FSEL) * HF + m_) * 512]);      \
        if (RDB) {                                                                           \
            _Pragma("unroll") for (int n_ = 0; n_ < NF; n_++)                                \
                bfr[n_] = *(const short8*)(&Bs[BUF][KS][b_rd + n_ * 512]);                   \
        }                                                                                    \
        STAGE_;                                                                              \
        __builtin_amdgcn_s_barrier();                                                        \
        asm volatile("s_waitcnt lgkmcnt(0)");                                                \
        __builtin_amdgcn_s_setprio(1);                                                       \
        _Pragma("unroll") for (int m_ = 0; m_ < HF; m_++)                                    \
            _Pragma("unroll") for (int n_ = 0; n_ < NF; n_++)                                \
                acc[(FSEL) * HF + m_][n_] = __builtin_amdgcn_mfma_f32_16x16x32_bf16(         \
                    afr_[m_], bfr[n_], acc[(FSEL) * HF + m_][n_], 0, 0, 0);                  \
        __builtin_amdgcn_s_setprio(0);                                                       \
        VMW_;                                                                                \
        __builtin_amdgcn_sched_barrier(0);                                                   \
        __builtin_amdgcn_s_barrier();                                                        \
    } while (0)

    const int NI = K >> 7;  // K-tile pairs
    int k0 = 0;             // elem offset of tile 2i

    if constexpr (BN == 256) {
        // prologue: tile0 (all 4 slots) + tile1 (B.k0, A.k0, B.k1); A.k1(t1) staged at p1.
        STAGEB(0, 0, 0);  STAGEA(0, 0, 0);  STAGEB(0, 1, 32); STAGEA(0, 1, 32);
        STAGEB(1, 0, 64); STAGEA(1, 0, 64); STAGEB(1, 1, 96);
        VM(6);  // tile0 fully landed; tile1's staged slots remain in flight
        __builtin_amdgcn_s_barrier();
        for (int i = 0; i < NI - 1; ++i, k0 += 128) {
            PHASE(0, 0, 0, 1, STAGEA(1, 1, k0 + 96),  );
            PHASE(0, 0, 1, 0, STAGEB(0, 0, k0 + 128), );
            PHASE(0, 1, 0, 1, STAGEA(0, 0, k0 + 128), );
            PHASE(0, 1, 1, 0, STAGEB(0, 1, k0 + 160), VM(6));
            PHASE(1, 0, 0, 1, STAGEA(0, 1, k0 + 160), );
            PHASE(1, 0, 1, 0, STAGEB(1, 0, k0 + 192), );
            PHASE(1, 1, 0, 1, STAGEA(1, 0, k0 + 192), );
            PHASE(1, 1, 1, 0, STAGEB(1, 1, k0 + 224), VM(6));
        }
        PHASE(0, 0, 0, 1, STAGEA(1, 1, k0 + 96), );
        PHASE(0, 0, 1, 0, , );
        PHASE(0, 1, 0, 1, , );
        PHASE(0, 1, 1, 0, , VM(0));
        PHASE(1, 0, 0, 1, , );
        PHASE(1, 0, 1, 0, , );
        PHASE(1, 1, 0, 1, , );
        PHASE(1, 1, 1, 0, , );
    } else {
        // prologue: tile0 both halves + tile1 k0 (9 loads); A11/B11 staged in P1.
        STAGEB(0, 0, 0);  STAGEA(0, 0, 0);  STAGEB(0, 1, 32); STAGEA(0, 1, 32);
        STAGEB(1, 0, 64); STAGEA(1, 0, 64);
        VM(6);  // tile0.k0 landed (first triple); 6 loads in flight
        __builtin_amdgcn_s_barrier();
        // merged 4-phase loop: each phase = full k-half slot (16 MFMA), stage = read+1 phase
        for (int i = 0; i < NI - 1; ++i, k0 += 128) {
            PHASE(0, 0, 0, 1, do { STAGEA(1, 1, k0 + 96);  STAGEB(1, 1, k0 + 96);  } while (0), VM(6));
            PHASE(0, 1, 0, 1, do { STAGEA(0, 0, k0 + 128); STAGEB(0, 0, k0 + 128); } while (0), VM(6));
            PHASE(1, 0, 0, 1, do { STAGEA(0, 1, k0 + 160); STAGEB(0, 1, k0 + 160); } while (0), VM(6));
            PHASE(1, 1, 0, 1, do { STAGEA(1, 0, k0 + 192); STAGEB(1, 0, k0 + 192); } while (0), VM(6));
        }
        PHASE(0, 0, 0, 1, do { STAGEA(1, 1, k0 + 96); STAGEB(1, 1, k0 + 96); } while (0), VM(6));
        PHASE(0, 1, 0, 1, , VM(3));
        PHASE(1, 0, 0, 1, , VM(0));
        PHASE(1, 1, 0, 1, , );
    }

#undef PHASE
#undef VM
#undef STAGEB
#undef STAGEA

    // epilogue: C row = q4*4+r, col = lr within each 16x16 fragment
#pragma unroll
    for (int m = 0; m < MF; m++) {
#pragma unroll
        for (int n = 0; n < NF; n++) {
            const int gn = n0 + wn + n * 16 + lr;
#pragma unroll
            for (int r = 0; r < 4; r++) {
                const long gm = m0 + wm + m * 16 + q4 * 4 + r;
                float v = acc[m][n][r];
                if constexpr (MODE == M_QKV) {
                    v = (v + bias[gn]) * scale;
                    ((u16*)out)[gm * N + gn] = f2bf(v);
                } else if constexpr (MODE == M_VT) {
                    v = v + bias[gm];
                    const long b = gn >> 11, s = gn & 2047;
                    ((u16*)out)[(b << 22) + gm * 2048 + s] = f2bf(v);
                } else if constexpr (MODE == M_H1) {
                    ((float*)out)[gm * N + gn] = v + bias[gn] + resid[gm * N + gn];
                } else if constexpr (MODE == M_RELU) {
                    ((u16*)out)[gm * N + gn] = f2bf(fmaxf(v, 0.0f));
                } else if constexpr (MODE == M_MUL) {
                    ((u16*)out)[gm * N + gn] = f2bf(v * bf2f(aux[gm * N + gn]));
                } else {  // M_ADD
                    ((float*)out)[gm * N + gn] = v + resid[gm * N + gn];
                }
            }
        }
    }
}

// ---------------- flash attention, computes O^T directly into the scrambled layout ----------------
__global__ __launch_bounds__(512) void attn_kernel(const u16* __restrict__ Q, const u16* __restrict__ Km,
                                                   const u16* __restrict__ Vt, u16* __restrict__ Oscr) {
    __shared__ u16 Ks[128 * 128];
    __shared__ u16 Vs[128 * 128];
    __shared__ u16 Ps[8][16 * 136];  // per-wave P strip, pitch 136 (8/bank on b128 reads)
    __shared__ float abuf[8][16];
    __shared__ float lbuf[8][16];
    const int tid = threadIdx.x, w = tid >> 6, lane = tid & 63;
    const int q4 = lane >> 4, lr = lane & 15;
    const int bh = blockIdx.y, b = bh >> 4, h = bh & 15;
    const int sw = blockIdx.x * 128 + w * 16;  // this wave's 16 query rows
    const long qkbase = ((long)b * 2048) * 2048 + h * 128;
    const long vtbase = ((long)b * 2048 + h * 128) * 2048;

    short8 qf[4];
    {
        const u16* qr = Q + qkbase + (long)(sw + lr) * 2048 + q4 * 8;
#pragma unroll
        for (int kk = 0; kk < 4; kk++) qf[kk] = *(const short8*)(qr + kk * 32);
    }
    float m_i[4], l_i[4];
#pragma unroll
    for (int r = 0; r < 4; r++) { m_i[r] = -1e30f; l_i[r] = 0.0f; }
    f32x4 oacc[8] = {};

    for (int t0 = 0; t0 < 2048; t0 += 128) {
        __syncthreads();
#pragma unroll
        for (int i = 0; i < 4; i++) {
            const int c = i * 512 + tid;           // linear 16B chunk 0..2047
            const int row = c >> 4;                // tile row 0..127
            const int lc = (c & 15) ^ (row & 15);  // logical chunk fetched into physical slot
            async16(Km + qkbase + (long)(t0 + row) * 2048 + lc * 8, (u16*)Ks + (i * 512 + w * 64) * 8);
            async16(Vt + vtbase + (long)row * 2048 + t0 + lc * 8, (u16*)Vs + (i * 512 + w * 64) * 8);
        }
        __syncthreads();
        // S strip [16 s][128 t] = q * K^T (scale pre-folded into q)
        f32x4 sacc[8] = {};
#pragma unroll
        for (int kk = 0; kk < 4; kk++) {
#pragma unroll
            for (int n = 0; n < 8; n++) {
                const int pc = (kk * 4 + q4) ^ lr;  // swizzled chunk
                short8 kf = *(const short8*)(Ks + ((n * 16 + lr) * 16 + pc) * 8);
                sacc[n] = __builtin_amdgcn_mfma_f32_16x16x32_bf16(qf[kk], kf, sacc[n], 0, 0, 0);
            }
        }
        // online softmax per s-row (row = q4*4+r, replicated across the 16 lanes of the quad)
        float al[4];
#pragma unroll
        for (int r = 0; r < 4; r++) {
            float mx = sacc[0][r];
#pragma unroll
            for (int n = 1; n < 8; n++) mx = fmaxf(mx, sacc[n][r]);
#pragma unroll
            for (int msk = 1; msk < 16; msk <<= 1) mx = fmaxf(mx, __shfl_xor(mx, msk, 64));
            const float mn = fmaxf(m_i[r], mx);
            al[r] = __expf(m_i[r] - mn);
            float rs = 0.0f;
#pragma unroll
            for (int n = 0; n < 8; n++) {
                float p = __expf(sacc[n][r] - mn);
                sacc[n][r] = p;
                rs += p;
            }
#pragma unroll
            for (int msk = 1; msk < 16; msk <<= 1) rs += __shfl_xor(rs, msk, 64);
            l_i[r] = l_i[r] * al[r] + rs;
            m_i[r] = mn;
        }
        // P -> LDS (bf16), alpha broadcast
#pragma unroll
        for (int n = 0; n < 8; n++)
#pragma unroll
            for (int r = 0; r < 4; r++)
                Ps[w][(q4 * 4 + r) * 136 + n * 16 + lr] = f2bf(sacc[n][r]);
        if (lr == 0) {
#pragma unroll
            for (int r = 0; r < 4; r++) abuf[w][q4 * 4 + r] = al[r];
        }
        __syncthreads();
        const float a_s = abuf[w][lr];
#pragma unroll
        for (int mm = 0; mm < 8; mm++) oacc[mm] *= a_s;
        // O^T[d][s] += Vt_tile(rows d) * P^T : A-frag from Vs rows, B-frag from Ps rows
#pragma unroll
        for (int kk = 0; kk < 4; kk++) {
            short8 pf = *(const short8*)(&Ps[w][lr * 136 + kk * 32 + q4 * 8]);
            const int pc = (kk * 4 + q4) ^ lr;
#pragma unroll
            for (int mm = 0; mm < 8; mm++) {
                short8 vf = *(const short8*)(Vs + ((mm * 16 + lr) * 16 + pc) * 8);
                oacc[mm] = __builtin_amdgcn_mfma_f32_16x16x32_bf16(vf, pf, oacc[mm], 0, 0, 0);
            }
        }
    }
    if (lr == 0) {
#pragma unroll
        for (int r = 0; r < 4; r++) lbuf[w][q4 * 4 + r] = l_i[r];
    }
    __syncthreads();
    const float linv = 1.0f / lbuf[w][lr];
    // write O^T: row d = mm*16+q4*4+r, col s = sw+lr (16-lane contiguous bf16 stores)
#pragma unroll
    for (int mm = 0; mm < 8; mm++) {
#pragma unroll
        for (int r = 0; r < 4; r++) {
            const int d = mm * 16 + q4 * 4 + r;
            Oscr[vtbase + (long)d * 2048 + sw + lr] = f2bf(oacc[mm][r] * linv);
        }
    }
}

// ---------------- launch ----------------
// Workspace budget (112 MB total), lifetime-aliased:
//   [0,16)MB   : xn  -> scr -> hn      (sequential lives)
//   [16,80)MB  : qb|kb|vt (16 each) -> grelu (64) -> inter (in-place)
//   [80,112)MB : JIT bf16 weight region: {wq,wk,wv,wo} -> wg -> wu -> wd
//   h1 lives in d_out (fp32, fully overwritten before first read).
extern "C" void kernel_launch(void* const* d_in, const int* in_sizes, int n_in,
                              void* d_out, int out_size, void* d_ws, size_t ws_size,
                              hipStream_t stream) {
    const float* x  = (const float*)d_in[0];
    const float* wq = (const float*)d_in[1];
    const float* bq = (const float*)d_in[2];
    const float* wk = (const float*)d_in[3];
    const float* bk = (const float*)d_in[4];
    const float* wv = (const float*)d_in[5];
    const float* bv = (const float*)d_in[6];
    const float* wo = (const float*)d_in[7];
    const float* bo = (const float*)d_in[8];
    const float* wg = (const float*)d_in[9];
    const float* wu = (const float*)d_in[10];
    const float* wd = (const float*)d_in[11];
    const float* ga = (const float*)d_in[12];
    const float* gf = (const float*)d_in[13];

    char* ws = (char*)d_ws;
    const size_t MB = (size_t)1 << 20;
    u16*  xn    = (u16*)(ws + 0);
    u16*  scr   = (u16*)(ws + 0);            // alias: xn dead after projections
    u16*  hn    = (u16*)(ws + 0);            // alias: scr dead after o-proj
    u16*  qb    = (u16*)(ws + 16 * MB);
    u16*  kb    = (u16*)(ws + 32 * MB);
    u16*  vt    = (u16*)(ws + 48 * MB);
    u16*  grelu = (u16*)(ws + 16 * MB);      // 64 MB, alias over qb/kb/vt/pad
    u16*  inter = grelu;                     // in-place relu(g)*u
    u16*  wreg  = (u16*)(ws + 80 * MB);      // 32 MB JIT weight region
    u16*  wq_b  = wreg;
    u16*  wk_b  = wreg + 4 * MB;             // u16 elements: 8MB bytes each
    u16*  wv_b  = wreg + 8 * MB;
    u16*  wo_b  = wreg + 12 * MB;
    u16*  wbig  = wreg;                      // wg -> wu -> wd reuse
    float* h1   = (float*)d_out;

    // phase-A weights fp32 -> bf16
    cvt_k<<<4096, 256, 0, stream>>>(wq, wq_b);
    cvt_k<<<4096, 256, 0, stream>>>(wk, wk_b);
    cvt_k<<<4096, 256, 0, stream>>>(wv, wv_b);
    cvt_k<<<4096, 256, 0, stream>>>(wo, wo_b);

    rmsnorm_k<<<4096, 256, 0, stream>>>(x, ga, xn);

    const float qscale = 0.08838834764831843f;  // 1/sqrt(128)
    // Q: M=4096,N=2048 -> (4096/256)*(2048/128) = 256 wgs
    gemm8p<M_QKV, 128><<<256, 512, 0, stream>>>(xn, wq_b, bq, nullptr, nullptr, qb, 2048, 2048, qscale);
    gemm8p<M_QKV, 128><<<256, 512, 0, stream>>>(xn, wk_b, bk, nullptr, nullptr, kb, 2048, 2048, 1.0f);
    // V^T: roles swapped -> C[nv][(b,s)] = wv . xn^T, stored [b][nv][s]; M=2048,N=4096 -> 8*32=256 wgs
    gemm8p<M_VT, 128><<<256, 512, 0, stream>>>(wv_b, xn, bv, nullptr, nullptr, vt, 4096, 2048, 1.0f);

    attn_kernel<<<dim3(16, 32), 512, 0, stream>>>(qb, kb, vt, scr);

    // out-proj + residual: h1 = x + scr @ wo^T + bo   (h1 lives in d_out); 16*16=256 wgs
    gemm8p<M_H1, 128><<<256, 512, 0, stream>>>(scr, wo_b, bo, x, nullptr, h1, 2048, 2048, 1.0f);

    cvt_k<<<16384, 256, 0, stream>>>(wg, wbig);          // wq..wo dead now
    rmsnorm_k<<<4096, 256, 0, stream>>>(h1, gf, hn);

    // M=4096,N=8192 -> (4096/256)*(8192/256) = 512 wgs
    gemm8p<M_RELU, 256><<<512, 512, 0, stream>>>(hn, wbig, nullptr, nullptr, nullptr, grelu, 8192, 2048, 1.0f);

    cvt_k<<<16384, 256, 0, stream>>>(wu, wbig);          // wg dead
    gemm8p<M_MUL, 256><<<512, 512, 0, stream>>>(hn, wbig, nullptr, nullptr, grelu, inter, 8192, 2048, 1.0f);

    cvt_k<<<16384, 256, 0, stream>>>(wd, wbig);          // wu dead
    // down-proj: M=4096,N=2048,K=8192 -> 256 wgs
    gemm8p<M_ADD, 128><<<256, 512, 0, stream>>>(inter, wbig, nullptr, h1, nullptr, d_out, 2048, 8192, 1.0f);
}

// Round 4
// 1077.151 us; speedup vs baseline: 1.1592x; 1.0209x over previous
//
#include <hip/hip_runtime.h>

typedef __attribute__((ext_vector_type(8))) short short8;
typedef __attribute__((ext_vector_type(4))) float f32x4;
typedef __attribute__((ext_vector_type(4))) unsigned short us4;
typedef unsigned short u16;

__device__ __forceinline__ u16 f2bf(float f) {
    unsigned u = __builtin_bit_cast(unsigned, f);
    return (u16)((u + 0x7fffu + ((u >> 16) & 1u)) >> 16);
}
__device__ __forceinline__ float bf2f(u16 h) {
    unsigned u = ((unsigned)h) << 16;
    return __builtin_bit_cast(float, u);
}
__device__ __forceinline__ void async16(const void* g, void* l) {
    __builtin_amdgcn_global_load_lds((const __attribute__((address_space(1))) unsigned int*)g,
                                     (__attribute__((address_space(3))) unsigned int*)l,
                                     16, 0, 0);
}

// ---------------- elementwise fp32 -> bf16 conversion ----------------
__global__ __launch_bounds__(256) void cvt_k(const float* __restrict__ in, u16* __restrict__ out) {
    int i = (blockIdx.x * 256 + threadIdx.x) * 4;
    f32x4 v = *(const f32x4*)(in + i);
    us4 o;
    o[0] = f2bf(v[0]); o[1] = f2bf(v[1]); o[2] = f2bf(v[2]); o[3] = f2bf(v[3]);
    *(us4*)(out + i) = o;
}

// ---------------- rmsnorm (keeps source bug: MULTIPLY by sqrt(var+eps)) ----------------
__global__ __launch_bounds__(256) void rmsnorm_k(const float* __restrict__ X, const float* __restrict__ g,
                                                 u16* __restrict__ O) {
    const int row = blockIdx.x, tid = threadIdx.x;
    const float* xr = X + (long)row * 2048 + tid * 8;
    f32x4 v0 = *(const f32x4*)xr;
    f32x4 v1 = *(const f32x4*)(xr + 4);
    float ss = v0[0]*v0[0] + v0[1]*v0[1] + v0[2]*v0[2] + v0[3]*v0[3]
             + v1[0]*v1[0] + v1[1]*v1[1] + v1[2]*v1[2] + v1[3]*v1[3];
#pragma unroll
    for (int m = 1; m < 64; m <<= 1) ss += __shfl_xor(ss, m, 64);
    __shared__ float wsum[4];
    if ((tid & 63) == 0) wsum[tid >> 6] = ss;
    __syncthreads();
    float tot = wsum[0] + wsum[1] + wsum[2] + wsum[3];
    const float sc = sqrtf(tot * (1.0f / 2048.0f) + 1e-6f);
    const float* gr = g + tid * 8;
    f32x4 g0 = *(const f32x4*)gr, g1 = *(const f32x4*)(gr + 4);
    us4 o0, o1;
    o0[0] = f2bf(v0[0] * sc * g0[0]); o0[1] = f2bf(v0[1] * sc * g0[1]);
    o0[2] = f2bf(v0[2] * sc * g0[2]); o0[3] = f2bf(v0[3] * sc * g0[3]);
    o1[0] = f2bf(v1[0] * sc * g1[0]); o1[1] = f2bf(v1[1] * sc * g1[1]);
    o1[2] = f2bf(v1[2] * sc * g1[2]); o1[3] = f2bf(v1[3] * sc * g1[3]);
    u16* op = O + (long)row * 2048 + tid * 8;
    *(us4*)op = o0;
    *(us4*)(op + 4) = o1;
}

// ---------------- 8/4-phase 256xBN GEMM: C = A * W^T (bf16 in, fp32 acc) ----------------
// m201 template: BM=256, BK=64 (2 k-half slots of 32), 512 thr = 8 waves, double-buffered
// LDS (2 K-tiles), counted vmcnt, raw s_barrier, setprio, 16B-chunk XOR swizzle
// c^=(row>>1)&3 (pre-swizzled global source, linear gload_lds dest).
// BN=256: 8 phases / 2 K-tiles, 16 MFMA/phase, vmcnt(6) at P4/P8.
// BN=128: merged 4 phases / 2 K-tiles, each phase one full k-half slot, 16 MFMA,
//   stage = read+1 phase, vmcnt(6) every phase (P1-staged slots are read at P4).
// HAZARD RULE (round-2): never stage a slot in the phase that reads it.
// SCHEDULING RULE (round-3, m141/m201): NO sched_barrier(0), NO ":::memory" clobbers —
//   MFMA<-ds_read ordering is compiler-visible dataflow; slot-overwrite ordering is
//   alias-enforced vs async16; pinning the scheduler cost ~2x (768 TF @ 33% MfmaUtil).
enum { M_QKV = 0, M_VT = 1, M_H1 = 2, M_RELU = 3, M_MUL = 4, M_ADD = 5 };

template <int MODE, int BN>
__global__ __launch_bounds__(512, 2) void gemm8p(const u16* __restrict__ A, const u16* __restrict__ W,
                                                 const float* __restrict__ bias, const float* resid,
                                                 const u16* aux, void* out,
                                                 int N, int K, float scale) {
    constexpr int MF = BN / 32;      // m-frags per wave (8 or 4)
    constexpr int HF = 4;            // m-frags per phase (both variants)
    constexpr int NF = 4;            // n-frags per wave
    constexpr int BSLOT = BN * 32;   // u16 elems per B k-half slot
    __shared__ alignas(16) u16 As[2][2][8192];
    __shared__ alignas(16) u16 Bs[2][2][BSLOT];

    const int tid = threadIdx.x, wv = tid >> 6, lane = tid & 63;
    const int q4 = lane >> 4, lr = lane & 15;
    const int wm = (BN == 256) ? (wv >> 2) * 128 : (wv >> 1) * 64;
    const int wn = (BN == 256) ? (wv & 3) * 64 : (wv & 1) * 64;

    // bijective XCD-chunked workgroup swizzle (m204)
    const int ntn = N / BN;
    int wg = blockIdx.x;
    {
        const int nwg = gridDim.x, q = nwg >> 3, r = nwg & 7, x = wg & 7, l = wg >> 3;
        wg = (x < r ? x * (q + 1) : r * (q + 1) + (x - r) * q) + l;
    }
    const long m0 = (long)(wg / ntn) * 256;
    const int n0 = (wg % ntn) * BN;

    // swizzled LDS fragment-read offsets (elems): row*32 + (q4 ^ ((row>>1)&3))*8
    const int cswz = (q4 ^ ((lr >> 1) & 3)) * 8;
    const int a_rd = (wm + lr) * 32 + cswz;
    const int b_rd = (wn + lr) * 32 + cswz;

    // staging: linear LDS dest (wave base + lane*16B), pre-swizzled global source
    const int srow = tid >> 2;                          // row within 128-row round
    const int slc = ((tid & 3) ^ ((srow >> 1) & 3)) * 8; // logical chunk elem offset
    const u16* gA0 = A + (m0 + srow) * (long)K + slc;
    const u16* gA1 = gA0 + 128 * (long)K;
    const u16* gB0 = W + ((long)n0 + srow) * K + slc;
    const u16* gB1 = (BN == 256) ? gB0 + 128 * (long)K : gB0;

    f32x4 acc[MF][NF] = {};
    short8 bfr[NF];

#define STAGEA(BUF, KS, KOFF) do {                       \
        u16* d_ = &As[BUF][KS][wv * 512];                \
        async16(gA0 + (KOFF), d_);                       \
        async16(gA1 + (KOFF), d_ + 4096); } while (0)
#define STAGEB(BUF, KS, KOFF) do {                       \
        u16* d_ = &Bs[BUF][KS][wv * 512];                \
        async16(gB0 + (KOFF), d_);                       \
        if (BN == 256) async16(gB1 + (KOFF), d_ + 4096); } while (0)
#define VM(N) asm volatile("s_waitcnt vmcnt(" #N ")")
#define PHASE(BUF, KS, FSEL, RDB, STAGE_, VMW_) do {                                         \
        short8 afr_[HF];                                                                     \
        _Pragma("unroll") for (int m_ = 0; m_ < HF; m_++)                                    \
            afr_[m_] = *(const short8*)(&As[BUF][KS][a_rd + ((FSEL) * HF + m_) * 512]);      \
        if (RDB) {                                                                           \
            _Pragma("unroll") for (int n_ = 0; n_ < NF; n_++)                                \
                bfr[n_] = *(const short8*)(&Bs[BUF][KS][b_rd + n_ * 512]);                   \
        }                                                                                    \
        STAGE_;                                                                              \
        __builtin_amdgcn_s_barrier();                                                        \
        asm volatile("s_waitcnt lgkmcnt(0)");                                                \
        __builtin_amdgcn_s_setprio(1);                                                       \
        _Pragma("unroll") for (int m_ = 0; m_ < HF; m_++)                                    \
            _Pragma("unroll") for (int n_ = 0; n_ < NF; n_++)                                \
                acc[(FSEL) * HF + m_][n_] = __builtin_amdgcn_mfma_f32_16x16x32_bf16(         \
                    afr_[m_], bfr[n_], acc[(FSEL) * HF + m_][n_], 0, 0, 0);                  \
        __builtin_amdgcn_s_setprio(0);                                                       \
        VMW_;                                                                                \
        __builtin_amdgcn_s_barrier();                                                        \
    } while (0)

    const int NI = K >> 7;  // K-tile pairs
    int k0 = 0;             // elem offset of tile 2i

    if constexpr (BN == 256) {
        // prologue: tile0 (all 4 slots) + tile1 (B.k0, A.k0, B.k1); A.k1(t1) staged at p1.
        STAGEB(0, 0, 0);  STAGEA(0, 0, 0);  STAGEB(0, 1, 32); STAGEA(0, 1, 32);
        STAGEB(1, 0, 64); STAGEA(1, 0, 64); STAGEB(1, 1, 96);
        VM(6);  // tile0 fully landed; tile1's staged slots remain in flight
        __builtin_amdgcn_s_barrier();
        for (int i = 0; i < NI - 1; ++i, k0 += 128) {
            PHASE(0, 0, 0, 1, STAGEA(1, 1, k0 + 96),  );
            PHASE(0, 0, 1, 0, STAGEB(0, 0, k0 + 128), );
            PHASE(0, 1, 0, 1, STAGEA(0, 0, k0 + 128), );
            PHASE(0, 1, 1, 0, STAGEB(0, 1, k0 + 160), VM(6));
            PHASE(1, 0, 0, 1, STAGEA(0, 1, k0 + 160), );
            PHASE(1, 0, 1, 0, STAGEB(1, 0, k0 + 192), );
            PHASE(1, 1, 0, 1, STAGEA(1, 0, k0 + 192), );
            PHASE(1, 1, 1, 0, STAGEB(1, 1, k0 + 224), VM(6));
        }
        PHASE(0, 0, 0, 1, STAGEA(1, 1, k0 + 96), );
        PHASE(0, 0, 1, 0, , );
        PHASE(0, 1, 0, 1, , );
        PHASE(0, 1, 1, 0, , VM(0));
        PHASE(1, 0, 0, 1, , );
        PHASE(1, 0, 1, 0, , );
        PHASE(1, 1, 0, 1, , );
        PHASE(1, 1, 1, 0, , );
    } else {
        // prologue: tile0 both halves + tile1 k0 (9 loads); A11/B11 staged in P1.
        STAGEB(0, 0, 0);  STAGEA(0, 0, 0);  STAGEB(0, 1, 32); STAGEA(0, 1, 32);
        STAGEB(1, 0, 64); STAGEA(1, 0, 64);
        VM(6);  // tile0.k0 landed (first triple); 6 loads in flight
        __builtin_amdgcn_s_barrier();
        // merged 4-phase loop: each phase = full k-half slot (16 MFMA), stage = read+1 phase
        for (int i = 0; i < NI - 1; ++i, k0 += 128) {
            PHASE(0, 0, 0, 1, do { STAGEA(1, 1, k0 + 96);  STAGEB(1, 1, k0 + 96);  } while (0), VM(6));
            PHASE(0, 1, 0, 1, do { STAGEA(0, 0, k0 + 128); STAGEB(0, 0, k0 + 128); } while (0), VM(6));
            PHASE(1, 0, 0, 1, do { STAGEA(0, 1, k0 + 160); STAGEB(0, 1, k0 + 160); } while (0), VM(6));
            PHASE(1, 1, 0, 1, do { STAGEA(1, 0, k0 + 192); STAGEB(1, 0, k0 + 192); } while (0), VM(6));
        }
        PHASE(0, 0, 0, 1, do { STAGEA(1, 1, k0 + 96); STAGEB(1, 1, k0 + 96); } while (0), VM(6));
        PHASE(0, 1, 0, 1, , VM(3));
        PHASE(1, 0, 0, 1, , VM(0));
        PHASE(1, 1, 0, 1, , );
    }

#undef PHASE
#undef VM
#undef STAGEB
#undef STAGEA

    // epilogue: C row = q4*4+r, col = lr within each 16x16 fragment
#pragma unroll
    for (int m = 0; m < MF; m++) {
#pragma unroll
        for (int n = 0; n < NF; n++) {
            const int gn = n0 + wn + n * 16 + lr;
#pragma unroll
            for (int r = 0; r < 4; r++) {
                const long gm = m0 + wm + m * 16 + q4 * 4 + r;
                float v = acc[m][n][r];
                if constexpr (MODE == M_QKV) {
                    v = (v + bias[gn]) * scale;
                    ((u16*)out)[gm * N + gn] = f2bf(v);
                } else if constexpr (MODE == M_VT) {
                    v = v + bias[gm];
                    const long b = gn >> 11, s = gn & 2047;
                    ((u16*)out)[(b << 22) + gm * 2048 + s] = f2bf(v);
                } else if constexpr (MODE == M_H1) {
                    ((float*)out)[gm * N + gn] = v + bias[gn] + resid[gm * N + gn];
                } else if constexpr (MODE == M_RELU) {
                    ((u16*)out)[gm * N + gn] = f2bf(fmaxf(v, 0.0f));
                } else if constexpr (MODE == M_MUL) {
                    ((u16*)out)[gm * N + gn] = f2bf(v * bf2f(aux[gm * N + gn]));
                } else {  // M_ADD
                    ((float*)out)[gm * N + gn] = v + resid[gm * N + gn];
                }
            }
        }
    }
}

// ---------------- flash attention, computes O^T directly into the scrambled layout ----------------
__global__ __launch_bounds__(512) void attn_kernel(const u16* __restrict__ Q, const u16* __restrict__ Km,
                                                   const u16* __restrict__ Vt, u16* __restrict__ Oscr) {
    __shared__ u16 Ks[128 * 128];
    __shared__ u16 Vs[128 * 128];
    __shared__ u16 Ps[8][16 * 136];  // per-wave P strip, pitch 136 (8/bank on b128 reads)
    __shared__ float abuf[8][16];
    __shared__ float lbuf[8][16];
    const int tid = threadIdx.x, w = tid >> 6, lane = tid & 63;
    const int q4 = lane >> 4, lr = lane & 15;
    const int bh = blockIdx.y, b = bh >> 4, h = bh & 15;
    const int sw = blockIdx.x * 128 + w * 16;  // this wave's 16 query rows
    const long qkbase = ((long)b * 2048) * 2048 + h * 128;
    const long vtbase = ((long)b * 2048 + h * 128) * 2048;

    short8 qf[4];
    {
        const u16* qr = Q + qkbase + (long)(sw + lr) * 2048 + q4 * 8;
#pragma unroll
        for (int kk = 0; kk < 4; kk++) qf[kk] = *(const short8*)(qr + kk * 32);
    }
    float m_i[4], l_i[4];
#pragma unroll
    for (int r = 0; r < 4; r++) { m_i[r] = -1e30f; l_i[r] = 0.0f; }
    f32x4 oacc[8] = {};

    for (int t0 = 0; t0 < 2048; t0 += 128) {
        __syncthreads();
#pragma unroll
        for (int i = 0; i < 4; i++) {
            const int c = i * 512 + tid;           // linear 16B chunk 0..2047
            const int row = c >> 4;                // tile row 0..127
            const int lc = (c & 15) ^ (row & 15);  // logical chunk fetched into physical slot
            async16(Km + qkbase + (long)(t0 + row) * 2048 + lc * 8, (u16*)Ks + (i * 512 + w * 64) * 8);
            async16(Vt + vtbase + (long)row * 2048 + t0 + lc * 8, (u16*)Vs + (i * 512 + w * 64) * 8);
        }
        __syncthreads();
        // S strip [16 s][128 t] = q * K^T (scale pre-folded into q)
        f32x4 sacc[8] = {};
#pragma unroll
        for (int kk = 0; kk < 4; kk++) {
#pragma unroll
            for (int n = 0; n < 8; n++) {
                const int pc = (kk * 4 + q4) ^ lr;  // swizzled chunk
                short8 kf = *(const short8*)(Ks + ((n * 16 + lr) * 16 + pc) * 8);
                sacc[n] = __builtin_amdgcn_mfma_f32_16x16x32_bf16(qf[kk], kf, sacc[n], 0, 0, 0);
            }
        }
        // online softmax per s-row (row = q4*4+r, replicated across the 16 lanes of the quad)
        float al[4];
#pragma unroll
        for (int r = 0; r < 4; r++) {
            float mx = sacc[0][r];
#pragma unroll
            for (int n = 1; n < 8; n++) mx = fmaxf(mx, sacc[n][r]);
#pragma unroll
            for (int msk = 1; msk < 16; msk <<= 1) mx = fmaxf(mx, __shfl_xor(mx, msk, 64));
            const float mn = fmaxf(m_i[r], mx);
            al[r] = __expf(m_i[r] - mn);
            float rs = 0.0f;
#pragma unroll
            for (int n = 0; n < 8; n++) {
                float p = __expf(sacc[n][r] - mn);
                sacc[n][r] = p;
                rs += p;
            }
#pragma unroll
            for (int msk = 1; msk < 16; msk <<= 1) rs += __shfl_xor(rs, msk, 64);
            l_i[r] = l_i[r] * al[r] + rs;
            m_i[r] = mn;
        }
        // P -> LDS (bf16), alpha broadcast
#pragma unroll
        for (int n = 0; n < 8; n++)
#pragma unroll
            for (int r = 0; r < 4; r++)
                Ps[w][(q4 * 4 + r) * 136 + n * 16 + lr] = f2bf(sacc[n][r]);
        if (lr == 0) {
#pragma unroll
            for (int r = 0; r < 4; r++) abuf[w][q4 * 4 + r] = al[r];
        }
        __syncthreads();
        const float a_s = abuf[w][lr];
#pragma unroll
        for (int mm = 0; mm < 8; mm++) oacc[mm] *= a_s;
        // O^T[d][s] += Vt_tile(rows d) * P^T : A-frag from Vs rows, B-frag from Ps rows
#pragma unroll
        for (int kk = 0; kk < 4; kk++) {
            short8 pf = *(const short8*)(&Ps[w][lr * 136 + kk * 32 + q4 * 8]);
            const int pc = (kk * 4 + q4) ^ lr;
#pragma unroll
            for (int mm = 0; mm < 8; mm++) {
                short8 vf = *(const short8*)(Vs + ((mm * 16 + lr) * 16 + pc) * 8);
                oacc[mm] = __builtin_amdgcn_mfma_f32_16x16x32_bf16(vf, pf, oacc[mm], 0, 0, 0);
            }
        }
    }
    if (lr == 0) {
#pragma unroll
        for (int r = 0; r < 4; r++) lbuf[w][q4 * 4 + r] = l_i[r];
    }
    __syncthreads();
    const float linv = 1.0f / lbuf[w][lr];
    // write O^T: row d = mm*16+q4*4+r, col s = sw+lr (16-lane contiguous bf16 stores)
#pragma unroll
    for (int mm = 0; mm < 8; mm++) {
#pragma unroll
        for (int r = 0; r < 4; r++) {
            const int d = mm * 16 + q4 * 4 + r;
            Oscr[vtbase + (long)d * 2048 + sw + lr] = f2bf(oacc[mm][r] * linv);
        }
    }
}

// ---------------- launch ----------------
// Workspace budget (112 MB total), lifetime-aliased:
//   [0,16)MB   : xn  -> scr -> hn      (sequential lives)
//   [16,80)MB  : qb|kb|vt (16 each) -> grelu (64) -> inter (in-place)
//   [80,112)MB : JIT bf16 weight region: {wq,wk,wv,wo} -> wg -> wu -> wd
//   h1 lives in d_out (fp32, fully overwritten before first read).
extern "C" void kernel_launch(void* const* d_in, const int* in_sizes, int n_in,
                              void* d_out, int out_size, void* d_ws, size_t ws_size,
                              hipStream_t stream) {
    const float* x  = (const float*)d_in[0];
    const float* wq = (const float*)d_in[1];
    const float* bq = (const float*)d_in[2];
    const float* wk = (const float*)d_in[3];
    const float* bk = (const float*)d_in[4];
    const float* wv = (const float*)d_in[5];
    const float* bv = (const float*)d_in[6];
    const float* wo = (const float*)d_in[7];
    const float* bo = (const float*)d_in[8];
    const float* wg = (const float*)d_in[9];
    const float* wu = (const float*)d_in[10];
    const float* wd = (const float*)d_in[11];
    const float* ga = (const float*)d_in[12];
    const float* gf = (const float*)d_in[13];

    char* ws = (char*)d_ws;
    const size_t MB = (size_t)1 << 20;
    u16*  xn    = (u16*)(ws + 0);
    u16*  scr   = (u16*)(ws + 0);            // alias: xn dead after projections
    u16*  hn    = (u16*)(ws + 0);            // alias: scr dead after o-proj
    u16*  qb    = (u16*)(ws + 16 * MB);
    u16*  kb    = (u16*)(ws + 32 * MB);
    u16*  vt    = (u16*)(ws + 48 * MB);
    u16*  grelu = (u16*)(ws + 16 * MB);      // 64 MB, alias over qb/kb/vt/pad
    u16*  inter = grelu;                     // in-place relu(g)*u
    u16*  wreg  = (u16*)(ws + 80 * MB);      // 32 MB JIT weight region
    u16*  wq_b  = wreg;
    u16*  wk_b  = wreg + 4 * MB;             // u16 elements: 8MB bytes each
    u16*  wv_b  = wreg + 8 * MB;
    u16*  wo_b  = wreg + 12 * MB;
    u16*  wbig  = wreg;                      // wg -> wu -> wd reuse
    float* h1   = (float*)d_out;

    // phase-A weights fp32 -> bf16
    cvt_k<<<4096, 256, 0, stream>>>(wq, wq_b);
    cvt_k<<<4096, 256, 0, stream>>>(wk, wk_b);
    cvt_k<<<4096, 256, 0, stream>>>(wv, wv_b);
    cvt_k<<<4096, 256, 0, stream>>>(wo, wo_b);

    rmsnorm_k<<<4096, 256, 0, stream>>>(x, ga, xn);

    const float qscale = 0.08838834764831843f;  // 1/sqrt(128)
    // Q: M=4096,N=2048 -> (4096/256)*(2048/128) = 256 wgs
    gemm8p<M_QKV, 128><<<256, 512, 0, stream>>>(xn, wq_b, bq, nullptr, nullptr, qb, 2048, 2048, qscale);
    gemm8p<M_QKV, 128><<<256, 512, 0, stream>>>(xn, wk_b, bk, nullptr, nullptr, kb, 2048, 2048, 1.0f);
    // V^T: roles swapped -> C[nv][(b,s)] = wv . xn^T, stored [b][nv][s]; M=2048,N=4096 -> 8*32=256 wgs
    gemm8p<M_VT, 128><<<256, 512, 0, stream>>>(wv_b, xn, bv, nullptr, nullptr, vt, 4096, 2048, 1.0f);

    attn_kernel<<<dim3(16, 32), 512, 0, stream>>>(qb, kb, vt, scr);

    // out-proj + residual: h1 = x + scr @ wo^T + bo   (h1 lives in d_out); 16*16=256 wgs
    gemm8p<M_H1, 128><<<256, 512, 0, stream>>>(scr, wo_b, bo, x, nullptr, h1, 2048, 2048, 1.0f);

    cvt_k<<<16384, 256, 0, stream>>>(wg, wbig);          // wq..wo dead now
    rmsnorm_k<<<4096, 256, 0, stream>>>(h1, gf, hn);

    // M=4096,N=8192 -> (4096/256)*(8192/256) = 512 wgs
    gemm8p<M_RELU, 256><<<512, 512, 0, stream>>>(hn, wbig, nullptr, nullptr, nullptr, grelu, 8192, 2048, 1.0f);

    cvt_k<<<16384, 256, 0, stream>>>(wu, wbig);          // wg dead
    gemm8p<M_MUL, 256><<<512, 512, 0, stream>>>(hn, wbig, nullptr, nullptr, grelu, inter, 8192, 2048, 1.0f);

    cvt_k<<<16384, 256, 0, stream>>>(wd, wbig);          // wu dead
    // down-proj: M=4096,N=2048,K=8192 -> 256 wgs
    gemm8p<M_ADD, 128><<<256, 512, 0, stream>>>(inter, wbig, nullptr, h1, nullptr, d_out, 2048, 8192, 1.0f);
}